// Round 4
// baseline (158.293 us; speedup 1.0000x reference)
//
#include <hip/hip_runtime.h>
#include <stdint.h>

#define B_ 2
#define T_ 2048
#define D_ 1024
#define H_ 16
#define DH_ 64
#define N3_ 3072
#define M_ 4096

typedef __attribute__((ext_vector_type(8))) short short8;
typedef __attribute__((ext_vector_type(4))) float f32x4;

typedef const uint32_t __attribute__((address_space(1))) gu32;
typedef uint32_t __attribute__((address_space(3))) lu32;

__device__ __forceinline__ void gload_lds16(const void* g, void* l) {
  __builtin_amdgcn_global_load_lds((gu32*)g, (lu32*)l, 16, 0, 0);
}

__device__ __forceinline__ uint16_t f2bf(float f) {
  union { float f; uint32_t u; } c; c.f = f;
  uint32_t u = c.u;
  return (uint16_t)((u + 0x7fffu + ((u >> 16) & 1u)) >> 16);
}

__device__ __forceinline__ uint32_t cvtpk_bf16(float lo, float hi) {
  uint32_t r;
  asm("v_cvt_pk_bf16_f32 %0, %1, %2" : "=v"(r) : "v"(lo), "v"(hi));
  return r;
}

// ---------------- pre-pass: f32 -> bf16 convert ----------------
__global__ void k_convert(const float* __restrict__ in, uint16_t* __restrict__ out, int n) {
  int stride = gridDim.x * blockDim.x * 4;
  for (int i = (blockIdx.x * blockDim.x + threadIdx.x) * 4; i < n; i += stride) {
    float4 v = *reinterpret_cast<const float4*>(in + i);
    ushort4 ov;
    ov.x = f2bf(v.x); ov.y = f2bf(v.y); ov.z = f2bf(v.z); ov.w = f2bf(v.w);
    *reinterpret_cast<ushort4*>(out + i) = ov;
  }
}

// ---------------- pre-pass: transpose W [K][N] f32 -> Wt [N][K] bf16 ----------------
__global__ void k_transpose_bf(const float* __restrict__ W, uint16_t* __restrict__ Wt,
                               int K, int N) {
  __shared__ float tile[32][33];
  const int nb = blockIdx.x * 32, kb = blockIdx.y * 32;
  const int tx = threadIdx.x, ty = threadIdx.y;  // (32,8)
#pragma unroll
  for (int i = 0; i < 4; i++)
    tile[ty + i * 8][tx] = W[(size_t)(kb + ty + i * 8) * N + nb + tx];
  __syncthreads();
#pragma unroll
  for (int i = 0; i < 4; i++) {
    const int nl = ty + i * 8;
    Wt[(size_t)(nb + nl) * K + kb + tx] = f2bf(tile[tx][nl]);
  }
}

// ---------------- pre-pass: V from qkv [t][d] -> Vt [bh][d][t] bf16 ----------------
__global__ __launch_bounds__(256)
void k_vtrans(const uint16_t* __restrict__ qkv, uint16_t* __restrict__ vt) {
  __shared__ uint16_t tl[64 * 64];
  const int tb = blockIdx.x, bh = blockIdx.y;
  const int b = bh >> 4, h = bh & 15;
  const uint16_t* Vg = qkv + (size_t)b * T_ * N3_ + 2 * H_ * DH_ + h * DH_;
  const int tid = threadIdx.x;
#pragma unroll
  for (int p = 0; p < 2; p++) {
    const int ch = p * 256 + tid;
    const int row = ch >> 3, cg = ch & 7;
    short8 v = *(const short8*)(Vg + (size_t)(tb * 64 + row) * N3_ + cg * 8);
    *(short8*)&tl[row * 64 + (cg ^ (row & 7)) * 8] = v;  // swizzled store
  }
  __syncthreads();
#pragma unroll
  for (int p = 0; p < 2; p++) {
    const int och = p * 256 + tid;
    const int d = och >> 3, ct = och & 7;
    uint16_t tmp[8];
#pragma unroll
    for (int j = 0; j < 8; j++) {
      const int row = ct * 8 + j;
      tmp[j] = tl[row * 64 + ((d >> 3) ^ (row & 7)) * 8 + (d & 7)];
    }
    short8 ov;
#pragma unroll
    for (int j = 0; j < 8; j++) ov[j] = (short)tmp[j];
    *(short8*)(vt + (size_t)bh * DH_ * T_ + (size_t)d * T_ + tb * 64 + ct * 8) = ov;
  }
}

// ---------------- GEMM: C[M][N] = A[M][K](bf16) * Bt[N][K](bf16)^T + bias ----------------
// QS: pre-scale Q columns (col < 1024) by 0.125*log2(e) so attention's QK^T
// emits log2-domain scores directly.
template <bool OUT_BF16, bool QS>
__global__ __launch_bounds__(256)
void k_gemm_bt(const uint16_t* __restrict__ A, const uint16_t* __restrict__ Bt,
               const float* __restrict__ bias, void* __restrict__ Cv,
               int M, int N, int K) {
  constexpr int BK = 32;
  __shared__ uint16_t As[128 * BK];
  __shared__ uint16_t Bs[128 * BK];
  const int tid = threadIdx.x;
  const int w = tid >> 6, lane = tid & 63;
  const int l16 = lane & 15, lg = lane >> 4;
  const int bm = blockIdx.x * 128, bn = blockIdx.y * 128;
  const int wr = (w >> 1) * 64, wc = (w & 1) * 64;
  f32x4 acc[4][4] = {};
  for (int kt = 0; kt < K; kt += BK) {
    __syncthreads();
#pragma unroll
    for (int j = 0; j < 2; j++) {
      const int slot = j * 4 + w;
      const int bbyte = slot * 1024 + lane * 16;
      const int row = bbyte >> 6;
      const int cole = (bbyte & 63) >> 1;
      gload_lds16(A + (size_t)(bm + row) * K + kt + cole, (char*)As + slot * 1024);
      gload_lds16(Bt + (size_t)(bn + row) * K + kt + cole, (char*)Bs + slot * 1024);
    }
    __syncthreads();
    short8 aF[4], bF[4];
#pragma unroll
    for (int f = 0; f < 4; f++) {
      aF[f] = *(const short8*)(As + (wr + f * 16 + l16) * BK + lg * 8);
      bF[f] = *(const short8*)(Bs + (wc + f * 16 + l16) * BK + lg * 8);
    }
#pragma unroll
    for (int mf = 0; mf < 4; mf++)
#pragma unroll
      for (int nf = 0; nf < 4; nf++)
        acc[mf][nf] = __builtin_amdgcn_mfma_f32_16x16x32_bf16(aF[mf], bF[nf], acc[mf][nf], 0, 0, 0);
  }
#pragma unroll
  for (int nf = 0; nf < 4; nf++) {
    const int col = bn + wc + nf * 16 + l16;
    const float bv = bias ? bias[col] : 0.0f;
    const float sc = (QS && col < H_ * DH_) ? 0.18033688f : 1.0f;  // 0.125*log2e
#pragma unroll
    for (int mf = 0; mf < 4; mf++) {
      const int row0 = bm + wr + mf * 16 + lg * 4;
#pragma unroll
      for (int r = 0; r < 4; r++) {
        const float v = (acc[mf][nf][r] + bv) * sc;
        if (OUT_BF16)
          ((uint16_t*)Cv)[(size_t)(row0 + r) * N + col] = f2bf(v);
        else
          ((float*)Cv)[(size_t)(row0 + r) * N + col] = v;
      }
    }
  }
}

// ---------------- flash attention v3: unpaired, defer-rescale ----------------
// Block (x,y): q-block jq = 31-x (big-first), head bh = y. 4 waves x 16 q-rows.
// Q pre-scaled to log2 domain by GEMM1. Swapped QK^T -> in-register softmax.
__global__ __launch_bounds__(256)
void k_attn3(const uint16_t* __restrict__ qkv, const uint16_t* __restrict__ vt,
             const float* __restrict__ sink, uint16_t* __restrict__ z) {
  __shared__ uint16_t Ks[2][64 * 64];
  __shared__ uint16_t Vs[2][64 * 64];
  __shared__ uint16_t Ps[4][16 * 64];
  const int jq = 31 - blockIdx.x;  // biggest blocks dispatch first
  const int bh = blockIdx.y;
  const int b = bh >> 4, h = bh & 15;
  const int tid = threadIdx.x, w = tid >> 6;
  const int lane = tid & 63, l16 = lane & 15, lg = lane >> 4;
  const uint16_t* Qg = qkv + (size_t)b * T_ * N3_ + h * DH_;
  const uint16_t* Kg = Qg + H_ * DH_;
  const uint16_t* Vtg = vt + (size_t)bh * DH_ * T_;
  const int ntiles = jq + 1;
  const int qb = jq * 64 + w * 16;
  short8 qF[2];
#pragma unroll
  for (int kf = 0; kf < 2; kf++)
    qF[kf] = *(const short8*)(Qg + (size_t)(qb + l16) * N3_ + kf * 32 + lg * 8);
  float m2 = sink[h] * 1.44269504f;     // sink as initial running max (log2)
  float l_ = (lg == 0) ? 1.0f : 0.0f;   // per-lane partial denominator
  f32x4 o[4] = {};

  auto STAGE = [&](int buf, int kt) {
#pragma unroll
    for (int p = 0; p < 2; p++) {
      const int chunk = p * 256 + tid;
      const int row = chunk >> 3, c = chunk & 7;
      const int cg = c ^ (row & 7);  // pre-swizzled global source (m173)
      gload_lds16(Kg + (size_t)(kt * 64 + row) * N3_ + cg * 8,
                  (char*)&Ks[buf][0] + (p * 256 + w * 64) * 16);
      gload_lds16(Vtg + (size_t)row * T_ + kt * 64 + cg * 8,
                  (char*)&Vs[buf][0] + (p * 256 + w * 64) * 16);
    }
  };

  STAGE(0, 0);
  __syncthreads();
  int cur = 0;
  for (int kt = 0; kt < ntiles; kt++) {
    if (kt + 1 < ntiles) STAGE(cur ^ 1, kt + 1);  // in flight during compute
    short8 kF[2][4];
#pragma unroll
    for (int kf = 0; kf < 2; kf++)
#pragma unroll
      for (int nf = 0; nf < 4; nf++) {
        const int row = nf * 16 + l16;
        const int cc = (kf * 4 + lg) ^ (l16 & 7);
        kF[kf][nf] = *(const short8*)(&Ks[cur][0] + row * 64 + cc * 8);
      }
    // S^T = K Q^T (log2 domain): s[nf][r] = S[key=kt*64+nf*16+lg*4+r][q=qb+l16]
    f32x4 s[4];
#pragma unroll
    for (int nf = 0; nf < 4; nf++) {
      f32x4 t = {};
      t = __builtin_amdgcn_mfma_f32_16x16x32_bf16(kF[0][nf], qF[0], t, 0, 0, 0);
      t = __builtin_amdgcn_mfma_f32_16x16x32_bf16(kF[1][nf], qF[1], t, 0, 0, 0);
      s[nf] = t;
    }
    const bool diag = (kt == jq);
    float mt = -3e38f;
    if (diag) {
#pragma unroll
      for (int nf = 0; nf < 4; nf++)
#pragma unroll
        for (int r = 0; r < 4; r++) {
          float v = s[nf][r];
          if (kt * 64 + nf * 16 + lg * 4 + r > qb + l16) v = -3e38f;
          s[nf][r] = v;
          mt = fmaxf(mt, v);
        }
    } else {
#pragma unroll
      for (int nf = 0; nf < 4; nf++)
#pragma unroll
        for (int r = 0; r < 4; r++) mt = fmaxf(mt, s[nf][r]);
    }
    mt = fmaxf(mt, __shfl_xor(mt, 16));
    mt = fmaxf(mt, __shfl_xor(mt, 32));
    // T13 defer-rescale: skip alpha/rescale while p stays bounded by 2^8
    if (!__all(mt <= m2 + 8.0f)) {
      const float mnew = fmaxf(m2, mt);
      const float alpha = exp2f(m2 - mnew);
      m2 = mnew;
      l_ *= alpha;
      float ar[4];
#pragma unroll
      for (int r = 0; r < 4; r++) ar[r] = __shfl(alpha, lg * 4 + r);
#pragma unroll
      for (int df = 0; df < 4; df++)
#pragma unroll
        for (int r = 0; r < 4; r++) o[df][r] *= ar[r];
    }
    float ps = 0.f;
#pragma unroll
    for (int nf = 0; nf < 4; nf++)
#pragma unroll
      for (int r = 0; r < 4; r++) {
        const float p = exp2f(s[nf][r] - m2);
        s[nf][r] = p;
        ps += p;
      }
    l_ += ps;
    // pack P -> per-wave LDS (swizzled b64 writes)
#pragma unroll
    for (int nf = 0; nf < 4; nf++) {
      uint2 pw;
      pw.x = cvtpk_bf16(s[nf][0], s[nf][1]);
      pw.y = cvtpk_bf16(s[nf][2], s[nf][3]);
      const int cc = (nf * 2 + (lg >> 1)) ^ (l16 & 7);
      *(uint2*)((char*)&Ps[w][0] + l16 * 128 + cc * 16 + (lg & 1) * 8) = pw;
    }
    // O += P V : P[q=l16][key=lg*8+j], V[d=l16][key=lg*8+j]
#pragma unroll
    for (int ks = 0; ks < 2; ks++) {
      const int cp = (ks * 4 + lg) ^ (l16 & 7);
      const short8 pF = *(const short8*)((char*)&Ps[w][0] + l16 * 128 + cp * 16);
#pragma unroll
      for (int df = 0; df < 4; df++) {
        const short8 vF = *(const short8*)((char*)&Vs[cur][0] + (df * 16 + l16) * 128 + cp * 16);
        o[df] = __builtin_amdgcn_mfma_f32_16x16x32_bf16(pF, vF, o[df], 0, 0, 0);
      }
    }
    __syncthreads();
    cur ^= 1;
  }
  // epilogue: reduce denominator partials, normalize, store
  l_ += __shfl_xor(l_, 16);
  l_ += __shfl_xor(l_, 32);
#pragma unroll
  for (int r = 0; r < 4; r++) {
    const float inv = 1.f / __shfl(l_, lg * 4 + r);
    const int qa = qb + lg * 4 + r;
    uint16_t* zp = z + (size_t)(b * T_ + qa) * (H_ * DH_) + h * DH_;
#pragma unroll
    for (int df = 0; df < 4; df++) zp[df * 16 + l16] = f2bf(o[df][r] * inv);
  }
}

extern "C" void kernel_launch(void* const* d_in, const int* in_sizes, int n_in,
                              void* d_out, int out_size, void* d_ws, size_t ws_size,
                              hipStream_t stream) {
  const float* x    = (const float*)d_in[0];
  const float* Wqkv = (const float*)d_in[1];
  const float* bqkv = (const float*)d_in[2];
  const float* Wo   = (const float*)d_in[3];
  const float* bo   = (const float*)d_in[4];
  const float* sink = (const float*)d_in[5];

  char* ws = (char*)d_ws;
  uint16_t* xb    = (uint16_t*)(ws);                        //  8 MB: x bf16; dead after gemm1
  uint16_t* vtb   = (uint16_t*)(ws);                        //  8 MB: Vt[bh][d][t] (aliases xb)
  uint16_t* wqkvt = (uint16_t*)(ws + (size_t)8  * 1048576); //  6 MB: W_QKV^T bf16
  uint16_t* wot   = (uint16_t*)(ws + (size_t)14 * 1048576); //  2 MB: W_O^T bf16
  uint16_t* qkvb  = (uint16_t*)(ws + (size_t)16 * 1048576); // 24 MB: qkv bf16
  uint16_t* zb    = (uint16_t*)(ws + (size_t)40 * 1048576); //  8 MB: z bf16

  k_convert<<<2048, 256, 0, stream>>>(x, xb, M_ * D_);
  k_transpose_bf<<<dim3(N3_ / 32, D_ / 32), dim3(32, 8), 0, stream>>>(Wqkv, wqkvt, D_, N3_);
  k_transpose_bf<<<dim3(D_ / 32, D_ / 32), dim3(32, 8), 0, stream>>>(Wo, wot, D_, D_);

  k_gemm_bt<true, true><<<dim3(M_ / 128, N3_ / 128), 256, 0, stream>>>(xb, wqkvt, bqkv, qkvb, M_, N3_, D_);
  k_vtrans<<<dim3(T_ / 64, B_ * H_), 256, 0, stream>>>(qkvb, vtb);
  k_attn3<<<dim3(32, B_ * H_), 256, 0, stream>>>(qkvb, vtb, sink, zb);
  k_gemm_bt<false, false><<<dim3(M_ / 128, D_ / 128), 256, 0, stream>>>(zb, wot, bo, d_out, M_, D_, D_);
}

// Round 5
// 133.739 us; speedup vs baseline: 1.1836x; 1.1836x over previous
//
#include <hip/hip_runtime.h>
#include <stdint.h>

#define B_ 2
#define T_ 2048
#define D_ 1024
#define H_ 16
#define DH_ 64
#define N3_ 3072
#define M_ 4096

typedef __attribute__((ext_vector_type(8))) short short8;
typedef __attribute__((ext_vector_type(4))) float f32x4;

typedef const uint32_t __attribute__((address_space(1))) gu32;
typedef uint32_t __attribute__((address_space(3))) lu32;

__device__ __forceinline__ void gload_lds16(const void* g, void* l) {
  __builtin_amdgcn_global_load_lds((gu32*)g, (lu32*)l, 16, 0, 0);
}

__device__ __forceinline__ uint16_t f2bf(float f) {
  union { float f; uint32_t u; } c; c.f = f;
  uint32_t u = c.u;
  return (uint16_t)((u + 0x7fffu + ((u >> 16) & 1u)) >> 16);
}

__device__ __forceinline__ uint32_t cvtpk_bf16(float lo, float hi) {
  uint32_t r;
  asm("v_cvt_pk_bf16_f32 %0, %1, %2" : "=v"(r) : "v"(lo), "v"(hi));
  return r;
}

// ---------------- pre-pass: f32 -> bf16 convert ----------------
__global__ void k_convert(const float* __restrict__ in, uint16_t* __restrict__ out, int n) {
  int stride = gridDim.x * blockDim.x * 4;
  for (int i = (blockIdx.x * blockDim.x + threadIdx.x) * 4; i < n; i += stride) {
    float4 v = *reinterpret_cast<const float4*>(in + i);
    ushort4 ov;
    ov.x = f2bf(v.x); ov.y = f2bf(v.y); ov.z = f2bf(v.z); ov.w = f2bf(v.w);
    *reinterpret_cast<ushort4*>(out + i) = ov;
  }
}

// ---------------- pre-pass: transpose W [K][N] f32 -> Wt [N][K] bf16 ----------------
__global__ void k_transpose_bf(const float* __restrict__ W, uint16_t* __restrict__ Wt,
                               int K, int N) {
  __shared__ float tile[32][33];
  const int nb = blockIdx.x * 32, kb = blockIdx.y * 32;
  const int tx = threadIdx.x, ty = threadIdx.y;  // (32,8)
#pragma unroll
  for (int i = 0; i < 4; i++)
    tile[ty + i * 8][tx] = W[(size_t)(kb + ty + i * 8) * N + nb + tx];
  __syncthreads();
#pragma unroll
  for (int i = 0; i < 4; i++) {
    const int nl = ty + i * 8;
    Wt[(size_t)(nb + nl) * K + kb + tx] = f2bf(tile[tx][nl]);
  }
}

// ---------------- pre-pass: V from qkv [t][d] -> Vt [bh][d][t] bf16 ----------------
__global__ __launch_bounds__(256)
void k_vtrans(const uint16_t* __restrict__ qkv, uint16_t* __restrict__ vt) {
  __shared__ uint16_t tl[64 * 64];
  const int tb = blockIdx.x, bh = blockIdx.y;
  const int b = bh >> 4, h = bh & 15;
  const uint16_t* Vg = qkv + (size_t)b * T_ * N3_ + 2 * H_ * DH_ + h * DH_;
  const int tid = threadIdx.x;
#pragma unroll
  for (int p = 0; p < 2; p++) {
    const int ch = p * 256 + tid;
    const int row = ch >> 3, cg = ch & 7;
    short8 v = *(const short8*)(Vg + (size_t)(tb * 64 + row) * N3_ + cg * 8);
    *(short8*)&tl[row * 64 + (cg ^ (row & 7)) * 8] = v;  // swizzled store
  }
  __syncthreads();
#pragma unroll
  for (int p = 0; p < 2; p++) {
    const int och = p * 256 + tid;
    const int d = och >> 3, ct = och & 7;
    uint16_t tmp[8];
#pragma unroll
    for (int j = 0; j < 8; j++) {
      const int row = ct * 8 + j;
      tmp[j] = tl[row * 64 + ((d >> 3) ^ (row & 7)) * 8 + (d & 7)];
    }
    short8 ov;
#pragma unroll
    for (int j = 0; j < 8; j++) ov[j] = (short)tmp[j];
    *(short8*)(vt + (size_t)bh * DH_ * T_ + (size_t)d * T_ + tb * 64 + ct * 8) = ov;
  }
}

// ---------------- GEMM: C[M][N] = A[M][K](bf16) * Bt[N][K](bf16)^T + bias ----------------
// QS: pre-scale Q columns (col < 1024) by 0.125*log2(e) so attention's QK^T
// emits log2-domain scores directly.
template <bool OUT_BF16, bool QS>
__global__ __launch_bounds__(256)
void k_gemm_bt(const uint16_t* __restrict__ A, const uint16_t* __restrict__ Bt,
               const float* __restrict__ bias, void* __restrict__ Cv,
               int M, int N, int K) {
  constexpr int BK = 32;
  __shared__ uint16_t As[128 * BK];
  __shared__ uint16_t Bs[128 * BK];
  const int tid = threadIdx.x;
  const int w = tid >> 6, lane = tid & 63;
  const int l16 = lane & 15, lg = lane >> 4;
  const int bm = blockIdx.x * 128, bn = blockIdx.y * 128;
  const int wr = (w >> 1) * 64, wc = (w & 1) * 64;
  f32x4 acc[4][4] = {};
  for (int kt = 0; kt < K; kt += BK) {
    __syncthreads();
#pragma unroll
    for (int j = 0; j < 2; j++) {
      const int slot = j * 4 + w;
      const int bbyte = slot * 1024 + lane * 16;
      const int row = bbyte >> 6;
      const int cole = (bbyte & 63) >> 1;
      gload_lds16(A + (size_t)(bm + row) * K + kt + cole, (char*)As + slot * 1024);
      gload_lds16(Bt + (size_t)(bn + row) * K + kt + cole, (char*)Bs + slot * 1024);
    }
    __syncthreads();
    short8 aF[4], bF[4];
#pragma unroll
    for (int f = 0; f < 4; f++) {
      aF[f] = *(const short8*)(As + (wr + f * 16 + l16) * BK + lg * 8);
      bF[f] = *(const short8*)(Bs + (wc + f * 16 + l16) * BK + lg * 8);
    }
#pragma unroll
    for (int mf = 0; mf < 4; mf++)
#pragma unroll
      for (int nf = 0; nf < 4; nf++)
        acc[mf][nf] = __builtin_amdgcn_mfma_f32_16x16x32_bf16(aF[mf], bF[nf], acc[mf][nf], 0, 0, 0);
  }
#pragma unroll
  for (int nf = 0; nf < 4; nf++) {
    const int col = bn + wc + nf * 16 + l16;
    const float bv = bias ? bias[col] : 0.0f;
    const float sc = (QS && col < H_ * DH_) ? 0.18033688f : 1.0f;  // 0.125*log2e
#pragma unroll
    for (int mf = 0; mf < 4; mf++) {
      const int row0 = bm + wr + mf * 16 + lg * 4;
#pragma unroll
      for (int r = 0; r < 4; r++) {
        const float v = (acc[mf][nf][r] + bv) * sc;
        if (OUT_BF16)
          ((uint16_t*)Cv)[(size_t)(row0 + r) * N + col] = f2bf(v);
        else
          ((float*)Cv)[(size_t)(row0 + r) * N + col] = v;
      }
    }
  }
}

// ---------------- flash attention v4: 8-wave paired blocks ----------------
// Flat grid 512. XCD decode: 4 heads per XCD (K/V L2-resident per XCD).
// Block handles q-blocks {jp, 31-jp}: waves 0-3 -> jp, waves 4-7 -> 31-jp.
// One shared K/V staging per iteration (paired work-efficiency), 8 waves for
// latency hiding. Q pre-scaled to log2 domain by GEMM1.
__global__ __launch_bounds__(512, 4)
void k_attn4(const uint16_t* __restrict__ qkv, const uint16_t* __restrict__ vt,
             const float* __restrict__ sink, uint16_t* __restrict__ z) {
  __shared__ uint16_t Ks[2][64 * 64];
  __shared__ uint16_t Vs[2][64 * 64];
  __shared__ uint16_t Ps[8][16 * 64];
  const int bid = blockIdx.x;
  const int bh = (bid & 7) * 4 + (bid >> 7);  // 4 consecutive heads per XCD
  const int jp = (bid >> 3) & 15;             // ascending: big pair first
  const int b = bh >> 4, h = bh & 15;
  const int tid = threadIdx.x, w = tid >> 6;
  const int lane = tid & 63, l16 = lane & 15, lg = lane >> 4;
  const int qs = w >> 2, wq = w & 3;
  const int qblk = qs ? (31 - jp) : jp;
  const int ntiles = 32 - jp;
  const int qb = qblk * 64 + wq * 16;
  const uint16_t* Qg = qkv + (size_t)b * T_ * N3_ + h * DH_;
  const uint16_t* Kg = Qg + H_ * DH_;
  const uint16_t* Vtg = vt + (size_t)bh * DH_ * T_;
  short8 qF[2];
#pragma unroll
  for (int kf = 0; kf < 2; kf++)
    qF[kf] = *(const short8*)(Qg + (size_t)(qb + l16) * N3_ + kf * 32 + lg * 8);
  float m2 = sink[h] * 1.44269504f;     // sink as initial running max (log2)
  float l_ = (lg == 0) ? 1.0f : 0.0f;   // per-lane partial denominator
  f32x4 o[4] = {};

  auto STAGE = [&](int buf, int kt) {
    const int row = tid >> 3, c = tid & 7;
    const int cg = c ^ (row & 7);  // pre-swizzled global source (m173)
    gload_lds16(Kg + (size_t)(kt * 64 + row) * N3_ + cg * 8,
                (char*)&Ks[buf][0] + w * 1024 + lane * 16);
    gload_lds16(Vtg + (size_t)row * T_ + kt * 64 + cg * 8,
                (char*)&Vs[buf][0] + w * 1024 + lane * 16);
  };

  STAGE(0, 0);
  __syncthreads();
  int cur = 0;
  for (int kt = 0; kt < ntiles; kt++) {
    if (kt + 1 < ntiles) STAGE(cur ^ 1, kt + 1);  // in flight during compute
    if (kt <= qblk) {  // wave-uniform: qs0 waves idle past the diagonal
      short8 kF[2][4];
#pragma unroll
      for (int kf = 0; kf < 2; kf++)
#pragma unroll
        for (int nf = 0; nf < 4; nf++) {
          const int row = nf * 16 + l16;
          const int cc = (kf * 4 + lg) ^ (l16 & 7);
          kF[kf][nf] = *(const short8*)(&Ks[cur][0] + row * 64 + cc * 8);
        }
      // S^T = K Q^T (log2): s[nf][r] = S[key=kt*64+nf*16+lg*4+r][q=qb+l16]
      f32x4 s[4];
      __builtin_amdgcn_s_setprio(1);
#pragma unroll
      for (int nf = 0; nf < 4; nf++) {
        f32x4 t = {};
        t = __builtin_amdgcn_mfma_f32_16x16x32_bf16(kF[0][nf], qF[0], t, 0, 0, 0);
        t = __builtin_amdgcn_mfma_f32_16x16x32_bf16(kF[1][nf], qF[1], t, 0, 0, 0);
        s[nf] = t;
      }
      __builtin_amdgcn_s_setprio(0);
      const bool diag = (kt == qblk);
      float mt = -3e38f;
      if (diag) {
#pragma unroll
        for (int nf = 0; nf < 4; nf++)
#pragma unroll
          for (int r = 0; r < 4; r++) {
            float v = s[nf][r];
            if (kt * 64 + nf * 16 + lg * 4 + r > qb + l16) v = -3e38f;
            s[nf][r] = v;
            mt = fmaxf(mt, v);
          }
      } else {
#pragma unroll
        for (int nf = 0; nf < 4; nf++)
#pragma unroll
          for (int r = 0; r < 4; r++) mt = fmaxf(mt, s[nf][r]);
      }
      mt = fmaxf(mt, __shfl_xor(mt, 16));
      mt = fmaxf(mt, __shfl_xor(mt, 32));
      // T13 defer-rescale: skip alpha/rescale while p stays bounded by 2^8
      if (!__all(mt <= m2 + 8.0f)) {
        const float mnew = fmaxf(m2, mt);
        const float alpha = exp2f(m2 - mnew);
        m2 = mnew;
        l_ *= alpha;
        float ar[4];
#pragma unroll
        for (int r = 0; r < 4; r++) ar[r] = __shfl(alpha, lg * 4 + r);
#pragma unroll
        for (int df = 0; df < 4; df++)
#pragma unroll
          for (int r = 0; r < 4; r++) o[df][r] *= ar[r];
      }
      float ps = 0.f;
#pragma unroll
      for (int nf = 0; nf < 4; nf++)
#pragma unroll
        for (int r = 0; r < 4; r++) {
          const float p = exp2f(s[nf][r] - m2);
          s[nf][r] = p;
          ps += p;
        }
      l_ += ps;
      // pack P -> per-wave LDS (swizzled b64 writes)
#pragma unroll
      for (int nf = 0; nf < 4; nf++) {
        uint2 pw;
        pw.x = cvtpk_bf16(s[nf][0], s[nf][1]);
        pw.y = cvtpk_bf16(s[nf][2], s[nf][3]);
        const int cc = (nf * 2 + (lg >> 1)) ^ (l16 & 7);
        *(uint2*)((char*)&Ps[w][0] + l16 * 128 + cc * 16 + (lg & 1) * 8) = pw;
      }
      // O += P V : P[q=l16][key=lg*8+j], V[d=l16][key=lg*8+j]
      __builtin_amdgcn_s_setprio(1);
#pragma unroll
      for (int ks = 0; ks < 2; ks++) {
        const int cp = (ks * 4 + lg) ^ (l16 & 7);
        const short8 pF = *(const short8*)((char*)&Ps[w][0] + l16 * 128 + cp * 16);
#pragma unroll
        for (int df = 0; df < 4; df++) {
          const short8 vF = *(const short8*)((char*)&Vs[cur][0] + (df * 16 + l16) * 128 + cp * 16);
          o[df] = __builtin_amdgcn_mfma_f32_16x16x32_bf16(pF, vF, o[df], 0, 0, 0);
        }
      }
      __builtin_amdgcn_s_setprio(0);
    }
    __syncthreads();
    cur ^= 1;
  }
  // epilogue: reduce denominator partials, normalize, store
  l_ += __shfl_xor(l_, 16);
  l_ += __shfl_xor(l_, 32);
#pragma unroll
  for (int r = 0; r < 4; r++) {
    const float inv = 1.f / __shfl(l_, lg * 4 + r);
    const int qa = qb + lg * 4 + r;
    uint16_t* zp = z + (size_t)(b * T_ + qa) * (H_ * DH_) + h * DH_;
#pragma unroll
    for (int df = 0; df < 4; df++) zp[df * 16 + l16] = f2bf(o[df][r] * inv);
  }
}

extern "C" void kernel_launch(void* const* d_in, const int* in_sizes, int n_in,
                              void* d_out, int out_size, void* d_ws, size_t ws_size,
                              hipStream_t stream) {
  const float* x    = (const float*)d_in[0];
  const float* Wqkv = (const float*)d_in[1];
  const float* bqkv = (const float*)d_in[2];
  const float* Wo   = (const float*)d_in[3];
  const float* bo   = (const float*)d_in[4];
  const float* sink = (const float*)d_in[5];

  char* ws = (char*)d_ws;
  uint16_t* xb    = (uint16_t*)(ws);                        //  8 MB: x bf16; dead after gemm1
  uint16_t* vtb   = (uint16_t*)(ws);                        //  8 MB: Vt[bh][d][t] (aliases xb)
  uint16_t* wqkvt = (uint16_t*)(ws + (size_t)8  * 1048576); //  6 MB: W_QKV^T bf16
  uint16_t* wot   = (uint16_t*)(ws + (size_t)14 * 1048576); //  2 MB: W_O^T bf16
  uint16_t* qkvb  = (uint16_t*)(ws + (size_t)16 * 1048576); // 24 MB: qkv bf16
  uint16_t* zb    = (uint16_t*)(ws + (size_t)40 * 1048576); //  8 MB: z bf16

  k_convert<<<2048, 256, 0, stream>>>(x, xb, M_ * D_);
  k_transpose_bf<<<dim3(N3_ / 32, D_ / 32), dim3(32, 8), 0, stream>>>(Wqkv, wqkvt, D_, N3_);
  k_transpose_bf<<<dim3(D_ / 32, D_ / 32), dim3(32, 8), 0, stream>>>(Wo, wot, D_, D_);

  k_gemm_bt<true, true><<<dim3(M_ / 128, N3_ / 128), 256, 0, stream>>>(xb, wqkvt, bqkv, qkvb, M_, N3_, D_);
  k_vtrans<<<dim3(T_ / 64, B_ * H_), 256, 0, stream>>>(qkvb, vtb);
  k_attn4<<<dim3(512), 512, 0, stream>>>(qkvb, vtb, sink, zb);
  k_gemm_bt<false, false><<<dim3(M_ / 128, D_ / 128), 256, 0, stream>>>(zb, wot, bo, d_out, M_, D_, D_);
}

// Round 7
// 125.504 us; speedup vs baseline: 1.2613x; 1.0656x over previous
//
#include <hip/hip_runtime.h>
#include <stdint.h>

#define B_ 2
#define T_ 2048
#define D_ 1024
#define H_ 16
#define DH_ 64
#define N3_ 3072
#define M_ 4096

typedef __attribute__((ext_vector_type(8))) short short8;
typedef __attribute__((ext_vector_type(4))) float f32x4;

typedef const uint32_t __attribute__((address_space(1))) gu32;
typedef uint32_t __attribute__((address_space(3))) lu32;

__device__ __forceinline__ void gload_lds16(const void* g, void* l) {
  __builtin_amdgcn_global_load_lds((gu32*)g, (lu32*)l, 16, 0, 0);
}

__device__ __forceinline__ uint16_t f2bf(float f) {
  union { float f; uint32_t u; } c; c.f = f;
  uint32_t u = c.u;
  return (uint16_t)((u + 0x7fffu + ((u >> 16) & 1u)) >> 16);
}

__device__ __forceinline__ uint32_t cvtpk_bf16(float lo, float hi) {
  uint32_t r;
  asm("v_cvt_pk_bf16_f32 %0, %1, %2" : "=v"(r) : "v"(lo), "v"(hi));
  return r;
}

// ---------------- fused pre-pass: convert x + transpose both W ----------------
// blocks [0,1024): x f32->bf16 ; [1024,4096): Wqkv^T ; [4096,5120): Wo^T
__global__ __launch_bounds__(256)
void k_prep(const float* __restrict__ x, const float* __restrict__ Wqkv,
            const float* __restrict__ Wo, uint16_t* __restrict__ xb,
            uint16_t* __restrict__ wqkvt, uint16_t* __restrict__ wot) {
  const int bid = blockIdx.x, tid = threadIdx.x;
  if (bid < 1024) {
#pragma unroll
    for (int it = 0; it < 4; it++) {
      const int i = (bid * 256 + tid) * 4 + it * 1048576;
      float4 v = *reinterpret_cast<const float4*>(x + i);
      ushort4 ov;
      ov.x = f2bf(v.x); ov.y = f2bf(v.y); ov.z = f2bf(v.z); ov.w = f2bf(v.w);
      *reinterpret_cast<ushort4*>(xb + i) = ov;
    }
    return;
  }
  __shared__ float tile[32][33];
  const float* W; uint16_t* Wt; int K, N, nb, kb;
  if (bid < 4096) {
    const int idx = bid - 1024;
    W = Wqkv; Wt = wqkvt; K = D_; N = N3_;
    nb = (idx % 96) * 32; kb = (idx / 96) * 32;
  } else {
    const int idx = bid - 4096;
    W = Wo; Wt = wot; K = D_; N = D_;
    nb = (idx & 31) * 32; kb = (idx >> 5) * 32;
  }
  const int tx = tid & 31, ty = tid >> 5;
#pragma unroll
  for (int i = 0; i < 4; i++)
    tile[ty + i * 8][tx] = W[(size_t)(kb + ty + i * 8) * N + nb + tx];
  __syncthreads();
#pragma unroll
  for (int i = 0; i < 4; i++) {
    const int nl = ty + i * 8;
    Wt[(size_t)(nb + nl) * K + kb + tx] = f2bf(tile[tx][nl]);
  }
}

// ---------------- GEMM: C[M][N] = A[M][K](bf16) * Bt[N][K](bf16)^T + bias ----------------
// QS: pre-scale Q columns (col < 1024) by 0.125*log2(e).
// VT: V columns (col >= 2048) are written TRANSPOSED to vtO[bh][d][t] (b64
//     packed) instead of to Cv - fuses the old k_vtrans kernel.
template <bool OUT_BF16, bool QS, bool VT>
__global__ __launch_bounds__(256)
void k_gemm_bt(const uint16_t* __restrict__ A, const uint16_t* __restrict__ Bt,
               const float* __restrict__ bias, void* __restrict__ Cv,
               uint16_t* __restrict__ vtO, int M, int N, int K) {
  constexpr int BK = 32;
  __shared__ uint16_t As[128 * BK];
  __shared__ uint16_t Bs[128 * BK];
  const int tid = threadIdx.x;
  const int w = tid >> 6, lane = tid & 63;
  const int l16 = lane & 15, lg = lane >> 4;
  const int bm = blockIdx.x * 128, bn = blockIdx.y * 128;
  const int wr = (w >> 1) * 64, wc = (w & 1) * 64;
  f32x4 acc[4][4] = {};
  for (int kt = 0; kt < K; kt += BK) {
    __syncthreads();
#pragma unroll
    for (int j = 0; j < 2; j++) {
      const int slot = j * 4 + w;
      const int bbyte = slot * 1024 + lane * 16;
      const int row = bbyte >> 6;
      const int cole = (bbyte & 63) >> 1;
      gload_lds16(A + (size_t)(bm + row) * K + kt + cole, (char*)As + slot * 1024);
      gload_lds16(Bt + (size_t)(bn + row) * K + kt + cole, (char*)Bs + slot * 1024);
    }
    __syncthreads();
    short8 aF[4], bF[4];
#pragma unroll
    for (int f = 0; f < 4; f++) {
      aF[f] = *(const short8*)(As + (wr + f * 16 + l16) * BK + lg * 8);
      bF[f] = *(const short8*)(Bs + (wc + f * 16 + l16) * BK + lg * 8);
    }
#pragma unroll
    for (int mf = 0; mf < 4; mf++)
#pragma unroll
      for (int nf = 0; nf < 4; nf++)
        acc[mf][nf] = __builtin_amdgcn_mfma_f32_16x16x32_bf16(aF[mf], bF[nf], acc[mf][nf], 0, 0, 0);
  }
#pragma unroll
  for (int nf = 0; nf < 4; nf++) {
    const int col = bn + wc + nf * 16 + l16;
    const float bv = bias ? bias[col] : 0.0f;
    const float sc = (QS && col < H_ * DH_) ? 0.18033688f : 1.0f;  // 0.125*log2e
    const bool vcol = VT && (col >= 2 * H_ * DH_);
#pragma unroll
    for (int mf = 0; mf < 4; mf++) {
      const int row0 = bm + wr + mf * 16 + lg * 4;
      if (vcol) {
        // transposed V store: Vt[bh][d][t0..t0+3]
        const int cv = col - 2 * H_ * DH_;
        const int hh = cv >> 6, dd = cv & 63;
        const int bb = row0 >> 11, t0 = row0 & 2047;
        uint64_t p4 = 0;
#pragma unroll
        for (int r = 0; r < 4; r++)
          p4 |= (uint64_t)f2bf(acc[mf][nf][r] + bv) << (16 * r);
        *(uint64_t*)(vtO + ((size_t)(bb * 16 + hh) * DH_ + dd) * T_ + t0) = p4;
      } else {
#pragma unroll
        for (int r = 0; r < 4; r++) {
          const float v = (acc[mf][nf][r] + bv) * sc;
          if (OUT_BF16)
            ((uint16_t*)Cv)[(size_t)(row0 + r) * N + col] = f2bf(v);
          else
            ((float*)Cv)[(size_t)(row0 + r) * N + col] = v;
        }
      }
    }
  }
}

// ---------------- flash attention v4 (R5-proven): 8-wave paired blocks ----------------
// Flat grid 512. XCD decode: 4 heads per XCD. Block handles q-blocks {jp,31-jp}:
// waves 0-3 -> jp, waves 4-7 -> 31-jp. One shared K/V staging per iteration.
__global__ __launch_bounds__(512, 4)
void k_attn4(const uint16_t* __restrict__ qkv, const uint16_t* __restrict__ vt,
             const float* __restrict__ sink, uint16_t* __restrict__ z) {
  __shared__ uint16_t Ks[2][64 * 64];
  __shared__ uint16_t Vs[2][64 * 64];
  __shared__ uint16_t Ps[8][16 * 64];
  const int bid = blockIdx.x;
  const int bh = (bid & 7) * 4 + (bid >> 7);  // 4 consecutive heads per XCD
  const int jp = (bid >> 3) & 15;             // ascending: big pair first
  const int b = bh >> 4, h = bh & 15;
  const int tid = threadIdx.x, w = tid >> 6;
  const int lane = tid & 63, l16 = lane & 15, lg = lane >> 4;
  const int qs = w >> 2, wq = w & 3;
  const int qblk = qs ? (31 - jp) : jp;
  const int ntiles = 32 - jp;
  const int qb = qblk * 64 + wq * 16;
  const uint16_t* Qg = qkv + (size_t)b * T_ * N3_ + h * DH_;
  const uint16_t* Kg = Qg + H_ * DH_;
  const uint16_t* Vtg = vt + (size_t)bh * DH_ * T_;
  short8 qF[2];
#pragma unroll
  for (int kf = 0; kf < 2; kf++)
    qF[kf] = *(const short8*)(Qg + (size_t)(qb + l16) * N3_ + kf * 32 + lg * 8);
  float m2 = sink[h] * 1.44269504f;     // sink as initial running max (log2)
  float l_ = (lg == 0) ? 1.0f : 0.0f;   // per-lane partial denominator
  f32x4 o[4] = {};

  auto STAGE = [&](int buf, int kt) {
    const int row = tid >> 3, c = tid & 7;
    const int cg = c ^ (row & 7);  // pre-swizzled global source (m173)
    gload_lds16(Kg + (size_t)(kt * 64 + row) * N3_ + cg * 8,
                (char*)&Ks[buf][0] + w * 1024 + lane * 16);
    gload_lds16(Vtg + (size_t)row * T_ + kt * 64 + cg * 8,
                (char*)&Vs[buf][0] + w * 1024 + lane * 16);
  };

  STAGE(0, 0);
  __syncthreads();
  int cur = 0;
  for (int kt = 0; kt < ntiles; kt++) {
    if (kt + 1 < ntiles) STAGE(cur ^ 1, kt + 1);  // in flight during compute
    if (kt <= qblk) {  // wave-uniform: qs0 waves idle past the diagonal
      short8 kF[2][4];
#pragma unroll
      for (int kf = 0; kf < 2; kf++)
#pragma unroll
        for (int nf = 0; nf < 4; nf++) {
          const int row = nf * 16 + l16;
          const int cc = (kf * 4 + lg) ^ (l16 & 7);
          kF[kf][nf] = *(const short8*)(&Ks[cur][0] + row * 64 + cc * 8);
        }
      // S^T = K Q^T (log2): s[nf][r] = S[key=kt*64+nf*16+lg*4+r][q=qb+l16]
      f32x4 s[4];
      __builtin_amdgcn_s_setprio(1);
#pragma unroll
      for (int nf = 0; nf < 4; nf++) {
        f32x4 t = {};
        t = __builtin_amdgcn_mfma_f32_16x16x32_bf16(kF[0][nf], qF[0], t, 0, 0, 0);
        t = __builtin_amdgcn_mfma_f32_16x16x32_bf16(kF[1][nf], qF[1], t, 0, 0, 0);
        s[nf] = t;
      }
      __builtin_amdgcn_s_setprio(0);
      const bool diag = (kt == qblk);
      float mt = -3e38f;
      if (diag) {
#pragma unroll
        for (int nf = 0; nf < 4; nf++)
#pragma unroll
          for (int r = 0; r < 4; r++) {
            float v = s[nf][r];
            if (kt * 64 + nf * 16 + lg * 4 + r > qb + l16) v = -3e38f;
            s[nf][r] = v;
            mt = fmaxf(mt, v);
          }
      } else {
#pragma unroll
        for (int nf = 0; nf < 4; nf++)
#pragma unroll
          for (int r = 0; r < 4; r++) mt = fmaxf(mt, s[nf][r]);
      }
      mt = fmaxf(mt, __shfl_xor(mt, 16));
      mt = fmaxf(mt, __shfl_xor(mt, 32));
      // T13 defer-rescale: skip alpha/rescale while p stays bounded by 2^8
      if (!__all(mt <= m2 + 8.0f)) {
        const float mnew = fmaxf(m2, mt);
        const float alpha = exp2f(m2 - mnew);
        m2 = mnew;
        l_ *= alpha;
        float ar[4];
#pragma unroll
        for (int r = 0; r < 4; r++) ar[r] = __shfl(alpha, lg * 4 + r);
#pragma unroll
        for (int df = 0; df < 4; df++)
#pragma unroll
          for (int r = 0; r < 4; r++) o[df][r] *= ar[r];
      }
      float ps = 0.f;
#pragma unroll
      for (int nf = 0; nf < 4; nf++)
#pragma unroll
        for (int r = 0; r < 4; r++) {
          const float p = exp2f(s[nf][r] - m2);
          s[nf][r] = p;
          ps += p;
        }
      l_ += ps;
      // pack P -> per-wave LDS (swizzled b64 writes)
#pragma unroll
      for (int nf = 0; nf < 4; nf++) {
        uint2 pw;
        pw.x = cvtpk_bf16(s[nf][0], s[nf][1]);
        pw.y = cvtpk_bf16(s[nf][2], s[nf][3]);
        const int cc = (nf * 2 + (lg >> 1)) ^ (l16 & 7);
        *(uint2*)((char*)&Ps[w][0] + l16 * 128 + cc * 16 + (lg & 1) * 8) = pw;
      }
      // O += P V : P[q=l16][key=lg*8+j], V[d=l16][key=lg*8+j]
      __builtin_amdgcn_s_setprio(1);
#pragma unroll
      for (int ks = 0; ks < 2; ks++) {
        const int cp = (ks * 4 + lg) ^ (l16 & 7);
        const short8 pF = *(const short8*)((char*)&Ps[w][0] + l16 * 128 + cp * 16);
#pragma unroll
        for (int df = 0; df < 4; df++) {
          const short8 vF = *(const short8*)((char*)&Vs[cur][0] + (df * 16 + l16) * 128 + cp * 16);
          o[df] = __builtin_amdgcn_mfma_f32_16x16x32_bf16(pF, vF, o[df], 0, 0, 0);
        }
      }
      __builtin_amdgcn_s_setprio(0);
    }
    __syncthreads();
    cur ^= 1;
  }
  // epilogue: reduce denominator partials, normalize, store
  l_ += __shfl_xor(l_, 16);
  l_ += __shfl_xor(l_, 32);
#pragma unroll
  for (int r = 0; r < 4; r++) {
    const float inv = 1.f / __shfl(l_, lg * 4 + r);
    const int qa = qb + lg * 4 + r;
    uint16_t* zp = z + (size_t)(b * T_ + qa) * (H_ * DH_) + h * DH_;
#pragma unroll
    for (int df = 0; df < 4; df++) zp[df * 16 + l16] = f2bf(o[df][r] * inv);
  }
}

extern "C" void kernel_launch(void* const* d_in, const int* in_sizes, int n_in,
                              void* d_out, int out_size, void* d_ws, size_t ws_size,
                              hipStream_t stream) {
  const float* x    = (const float*)d_in[0];
  const float* Wqkv = (const float*)d_in[1];
  const float* bqkv = (const float*)d_in[2];
  const float* Wo   = (const float*)d_in[3];
  const float* bo   = (const float*)d_in[4];
  const float* sink = (const float*)d_in[5];

  // workspace layout (48 MB total):
  //  0- 8 MB : xb (x bf16; dead after gemm1)  /  zb (attn out; aliases xb)
  //  8-14 MB : W_QKV^T bf16
  // 14-16 MB : W_O^T bf16
  // 16-24 MB : Vt[bh][d][t] bf16 (written by gemm1 epilogue)
  // 24-48 MB : qkv bf16 (Q,K used; V region unwritten)
  char* ws = (char*)d_ws;
  uint16_t* xb    = (uint16_t*)(ws);
  uint16_t* zb    = (uint16_t*)(ws);
  uint16_t* wqkvt = (uint16_t*)(ws + (size_t)8  * 1048576);
  uint16_t* wot   = (uint16_t*)(ws + (size_t)14 * 1048576);
  uint16_t* vtb   = (uint16_t*)(ws + (size_t)16 * 1048576);
  uint16_t* qkvb  = (uint16_t*)(ws + (size_t)24 * 1048576);

  k_prep<<<5120, 256, 0, stream>>>(x, Wqkv, Wo, xb, wqkvt, wot);
  k_gemm_bt<true, true, true><<<dim3(M_ / 128, N3_ / 128), 256, 0, stream>>>(
      xb, wqkvt, bqkv, qkvb, vtb, M_, N3_, D_);
  k_attn4<<<dim3(512), 512, 0, stream>>>(qkvb, vtb, sink, zb);
  k_gemm_bt<false, false, false><<<dim3(M_ / 128, D_ / 128), 256, 0, stream>>>(
      zb, wot, bo, d_out, nullptr, M_, D_, D_);
}

// Round 8
// 123.080 us; speedup vs baseline: 1.2861x; 1.0197x over previous
//
#include <hip/hip_runtime.h>
#include <stdint.h>

#define B_ 2
#define T_ 2048
#define D_ 1024
#define H_ 16
#define DH_ 64
#define N3_ 3072
#define M_ 4096

typedef __attribute__((ext_vector_type(8))) short short8;
typedef __attribute__((ext_vector_type(4))) float f32x4;

typedef const uint32_t __attribute__((address_space(1))) gu32;
typedef uint32_t __attribute__((address_space(3))) lu32;

__device__ __forceinline__ void gload_lds16(const void* g, void* l) {
  __builtin_amdgcn_global_load_lds((gu32*)g, (lu32*)l, 16, 0, 0);
}

__device__ __forceinline__ uint16_t f2bf(float f) {
  union { float f; uint32_t u; } c; c.f = f;
  uint32_t u = c.u;
  return (uint16_t)((u + 0x7fffu + ((u >> 16) & 1u)) >> 16);
}

__device__ __forceinline__ uint32_t cvtpk_bf16(float lo, float hi) {
  uint32_t r;
  asm("v_cvt_pk_bf16_f32 %0, %1, %2" : "=v"(r) : "v"(lo), "v"(hi));
  return r;
}

// ---------------- fused pre-pass: convert x + transpose both W ----------------
// blocks [0,1024): x f32->bf16 ; [1024,4096): Wqkv^T ; [4096,5120): Wo^T
__global__ __launch_bounds__(256)
void k_prep(const float* __restrict__ x, const float* __restrict__ Wqkv,
            const float* __restrict__ Wo, uint16_t* __restrict__ xb,
            uint16_t* __restrict__ wqkvt, uint16_t* __restrict__ wot) {
  const int bid = blockIdx.x, tid = threadIdx.x;
  if (bid < 1024) {
#pragma unroll
    for (int it = 0; it < 4; it++) {
      const int i = (bid * 256 + tid) * 4 + it * 1048576;
      float4 v = *reinterpret_cast<const float4*>(x + i);
      ushort4 ov;
      ov.x = f2bf(v.x); ov.y = f2bf(v.y); ov.z = f2bf(v.z); ov.w = f2bf(v.w);
      *reinterpret_cast<ushort4*>(xb + i) = ov;
    }
    return;
  }
  __shared__ float tile[32][33];
  const float* W; uint16_t* Wt; int K, N, nb, kb;
  if (bid < 4096) {
    const int idx = bid - 1024;
    W = Wqkv; Wt = wqkvt; K = D_; N = N3_;
    nb = (idx % 96) * 32; kb = (idx / 96) * 32;
  } else {
    const int idx = bid - 4096;
    W = Wo; Wt = wot; K = D_; N = D_;
    nb = (idx & 31) * 32; kb = (idx >> 5) * 32;
  }
  const int tx = tid & 31, ty = tid >> 5;
#pragma unroll
  for (int i = 0; i < 4; i++)
    tile[ty + i * 8][tx] = W[(size_t)(kb + ty + i * 8) * N + nb + tx];
  __syncthreads();
#pragma unroll
  for (int i = 0; i < 4; i++) {
    const int nl = ty + i * 8;
    Wt[(size_t)(nb + nl) * K + kb + tx] = f2bf(tile[tx][nl]);
  }
}

// ---------------- GEMM: C[M][N] = A[M][K](bf16) * Bt[N][K](bf16)^T + bias ----------------
// QS: pre-scale Q columns (col < 1024) by 0.125*log2(e).
// VT: V columns (col >= 2048) are written TRANSPOSED to vtO[bh][d][t] (b64
//     packed) instead of to Cv - fuses the old k_vtrans kernel.
template <bool OUT_BF16, bool QS, bool VT>
__global__ __launch_bounds__(256)
void k_gemm_bt(const uint16_t* __restrict__ A, const uint16_t* __restrict__ Bt,
               const float* __restrict__ bias, void* __restrict__ Cv,
               uint16_t* __restrict__ vtO, int M, int N, int K) {
  constexpr int BK = 32;
  __shared__ uint16_t As[128 * BK];
  __shared__ uint16_t Bs[128 * BK];
  const int tid = threadIdx.x;
  const int w = tid >> 6, lane = tid & 63;
  const int l16 = lane & 15, lg = lane >> 4;
  const int bm = blockIdx.x * 128, bn = blockIdx.y * 128;
  const int wr = (w >> 1) * 64, wc = (w & 1) * 64;
  f32x4 acc[4][4] = {};
  for (int kt = 0; kt < K; kt += BK) {
    __syncthreads();
#pragma unroll
    for (int j = 0; j < 2; j++) {
      const int slot = j * 4 + w;
      const int bbyte = slot * 1024 + lane * 16;
      const int row = bbyte >> 6;
      const int cole = (bbyte & 63) >> 1;
      gload_lds16(A + (size_t)(bm + row) * K + kt + cole, (char*)As + slot * 1024);
      gload_lds16(Bt + (size_t)(bn + row) * K + kt + cole, (char*)Bs + slot * 1024);
    }
    __syncthreads();
    short8 aF[4], bF[4];
#pragma unroll
    for (int f = 0; f < 4; f++) {
      aF[f] = *(const short8*)(As + (wr + f * 16 + l16) * BK + lg * 8);
      bF[f] = *(const short8*)(Bs + (wc + f * 16 + l16) * BK + lg * 8);
    }
#pragma unroll
    for (int mf = 0; mf < 4; mf++)
#pragma unroll
      for (int nf = 0; nf < 4; nf++)
        acc[mf][nf] = __builtin_amdgcn_mfma_f32_16x16x32_bf16(aF[mf], bF[nf], acc[mf][nf], 0, 0, 0);
  }
#pragma unroll
  for (int nf = 0; nf < 4; nf++) {
    const int col = bn + wc + nf * 16 + l16;
    const float bv = bias ? bias[col] : 0.0f;
    const float sc = (QS && col < H_ * DH_) ? 0.18033688f : 1.0f;  // 0.125*log2e
    const bool vcol = VT && (col >= 2 * H_ * DH_);
#pragma unroll
    for (int mf = 0; mf < 4; mf++) {
      const int row0 = bm + wr + mf * 16 + lg * 4;
      if (vcol) {
        // transposed V store: Vt[bh][d][t0..t0+3]
        const int cv = col - 2 * H_ * DH_;
        const int hh = cv >> 6, dd = cv & 63;
        const int bb = row0 >> 11, t0 = row0 & 2047;
        uint64_t p4 = 0;
#pragma unroll
        for (int r = 0; r < 4; r++)
          p4 |= (uint64_t)f2bf(acc[mf][nf][r] + bv) << (16 * r);
        *(uint64_t*)(vtO + ((size_t)(bb * 16 + hh) * DH_ + dd) * T_ + t0) = p4;
      } else {
#pragma unroll
        for (int r = 0; r < 4; r++) {
          const float v = (acc[mf][nf][r] + bv) * sc;
          if (OUT_BF16)
            ((uint16_t*)Cv)[(size_t)(row0 + r) * N + col] = f2bf(v);
          else
            ((float*)Cv)[(size_t)(row0 + r) * N + col] = v;
        }
      }
    }
  }
}

// ---------------- flash attention v6: dual 64-tile per barrier ----------------
// attn4's proven per-tile geometry, but LDS holds 2 tiles per buffer: each
// iteration stages tiles {2k,2k+1} and computes both between ONE barrier pair.
// Flat grid 512; XCD decode (4 heads/XCD); waves 0-3 -> jp, 4-7 -> 31-jp.
__global__ __launch_bounds__(512, 4)
void k_attn6(const uint16_t* __restrict__ qkv, const uint16_t* __restrict__ vt,
             const float* __restrict__ sink, uint16_t* __restrict__ z) {
  __shared__ uint16_t Ks[2][2][64 * 64];   // [buf][half][key][d]
  __shared__ uint16_t Vs[2][2][64 * 64];   // [buf][half][d][key]
  __shared__ uint16_t Ps[8][16 * 64];
  const int bid = blockIdx.x;
  const int bh = (bid & 7) * 4 + (bid >> 7);  // 4 consecutive heads per XCD
  const int jp = (bid >> 3) & 15;             // ascending: big pair first
  const int b = bh >> 4, h = bh & 15;
  const int tid = threadIdx.x, w = tid >> 6;
  const int lane = tid & 63, l16 = lane & 15, lg = lane >> 4;
  const int qs = w >> 2, wq = w & 3;
  const int qblk = qs ? (31 - jp) : jp;
  const int NIT = (33 - jp) >> 1;  // 128-key iterations
  const int qb = qblk * 64 + wq * 16;
  const uint16_t* Qg = qkv + (size_t)b * T_ * N3_ + h * DH_;
  const uint16_t* Kg = Qg + H_ * DH_;
  const uint16_t* Vtg = vt + (size_t)bh * DH_ * T_;
  short8 qF[2];
#pragma unroll
  for (int kf = 0; kf < 2; kf++)
    qF[kf] = *(const short8*)(Qg + (size_t)(qb + l16) * N3_ + kf * 32 + lg * 8);
  float m2 = sink[h] * 1.44269504f;     // sink as initial running max (log2)
  float l_ = (lg == 0) ? 1.0f : 0.0f;   // per-lane partial denominator
  f32x4 o[4] = {};

  // stage one 64x64 K tile + one 64x64 Vt tile (attn4 geometry, per half)
  auto STAGE = [&](int buf, int half, int kt) {
    const int row = tid >> 3, c = tid & 7;
    const int cg = c ^ (row & 7);  // pre-swizzled global source (m173)
    gload_lds16(Kg + (size_t)(kt * 64 + row) * N3_ + cg * 8,
                (char*)&Ks[buf][half][0] + w * 1024 + lane * 16);
    gload_lds16(Vtg + (size_t)row * T_ + kt * 64 + cg * 8,
                (char*)&Vs[buf][half][0] + w * 1024 + lane * 16);
  };

  STAGE(0, 0, 0);
  if (jp < 31) STAGE(0, 1, 1);
  __syncthreads();
  int cur = 0;
  for (int kt2 = 0; kt2 < NIT; kt2++) {
    if (kt2 + 1 < NIT) {  // prefetch next pair (in flight during compute)
      STAGE(cur ^ 1, 0, 2 * kt2 + 2);
      STAGE(cur ^ 1, 1, 2 * kt2 + 3);
    }
#pragma unroll
    for (int half = 0; half < 2; half++) {
      const int sub = 2 * kt2 + half;
      if (sub <= qblk) {  // wave-uniform
        short8 kF[2][4];
#pragma unroll
        for (int kf = 0; kf < 2; kf++)
#pragma unroll
          for (int nf = 0; nf < 4; nf++) {
            const int row = nf * 16 + l16;
            const int cc = (kf * 4 + lg) ^ (l16 & 7);
            kF[kf][nf] = *(const short8*)(&Ks[cur][half][0] + row * 64 + cc * 8);
          }
        // S^T = K Q^T (log2): s[nf][r] = S[key=sub*64+nf*16+lg*4+r][q=qb+l16]
        f32x4 s[4];
        __builtin_amdgcn_s_setprio(1);
#pragma unroll
        for (int nf = 0; nf < 4; nf++) {
          f32x4 t = {};
          t = __builtin_amdgcn_mfma_f32_16x16x32_bf16(kF[0][nf], qF[0], t, 0, 0, 0);
          t = __builtin_amdgcn_mfma_f32_16x16x32_bf16(kF[1][nf], qF[1], t, 0, 0, 0);
          s[nf] = t;
        }
        __builtin_amdgcn_s_setprio(0);
        const bool diag = (sub == qblk);
        float mt = -3e38f;
        if (diag) {
#pragma unroll
          for (int nf = 0; nf < 4; nf++)
#pragma unroll
            for (int r = 0; r < 4; r++) {
              float v = s[nf][r];
              if (sub * 64 + nf * 16 + lg * 4 + r > qb + l16) v = -3e38f;
              s[nf][r] = v;
              mt = fmaxf(mt, v);
            }
        } else {
#pragma unroll
          for (int nf = 0; nf < 4; nf++)
#pragma unroll
            for (int r = 0; r < 4; r++) mt = fmaxf(mt, s[nf][r]);
        }
        mt = fmaxf(mt, __shfl_xor(mt, 16));
        mt = fmaxf(mt, __shfl_xor(mt, 32));
        // T13 defer-rescale: skip alpha/rescale while p stays bounded by 2^8
        if (!__all(mt <= m2 + 8.0f)) {
          const float mnew = fmaxf(m2, mt);
          const float alpha = exp2f(m2 - mnew);
          m2 = mnew;
          l_ *= alpha;
          float ar[4];
#pragma unroll
          for (int r = 0; r < 4; r++) ar[r] = __shfl(alpha, lg * 4 + r);
#pragma unroll
          for (int df = 0; df < 4; df++)
#pragma unroll
            for (int r = 0; r < 4; r++) o[df][r] *= ar[r];
        }
        float ps = 0.f;
#pragma unroll
        for (int nf = 0; nf < 4; nf++)
#pragma unroll
          for (int r = 0; r < 4; r++) {
            const float p = exp2f(s[nf][r] - m2);
            s[nf][r] = p;
            ps += p;
          }
        l_ += ps;
        // pack P -> per-wave LDS (swizzled b64 writes)
#pragma unroll
        for (int nf = 0; nf < 4; nf++) {
          uint2 pw;
          pw.x = cvtpk_bf16(s[nf][0], s[nf][1]);
          pw.y = cvtpk_bf16(s[nf][2], s[nf][3]);
          const int cc = (nf * 2 + (lg >> 1)) ^ (l16 & 7);
          *(uint2*)((char*)&Ps[w][0] + l16 * 128 + cc * 16 + (lg & 1) * 8) = pw;
        }
        // O += P V : P[q=l16][key=lg*8+j], V[d=l16][key=lg*8+j]
        __builtin_amdgcn_s_setprio(1);
#pragma unroll
        for (int ks = 0; ks < 2; ks++) {
          const int cp = (ks * 4 + lg) ^ (l16 & 7);
          const short8 pF = *(const short8*)((char*)&Ps[w][0] + l16 * 128 + cp * 16);
#pragma unroll
          for (int df = 0; df < 4; df++) {
            const short8 vF = *(const short8*)((char*)&Vs[cur][half][0] + (df * 16 + l16) * 128 + cp * 16);
            o[df] = __builtin_amdgcn_mfma_f32_16x16x32_bf16(pF, vF, o[df], 0, 0, 0);
          }
        }
        __builtin_amdgcn_s_setprio(0);
      }
    }
    __syncthreads();
    cur ^= 1;
  }
  // epilogue: reduce denominator partials, normalize, store
  l_ += __shfl_xor(l_, 16);
  l_ += __shfl_xor(l_, 32);
#pragma unroll
  for (int r = 0; r < 4; r++) {
    const float inv = 1.f / __shfl(l_, lg * 4 + r);
    const int qa = qb + lg * 4 + r;
    uint16_t* zp = z + (size_t)(b * T_ + qa) * (H_ * DH_) + h * DH_;
#pragma unroll
    for (int df = 0; df < 4; df++) zp[df * 16 + l16] = f2bf(o[df][r] * inv);
  }
}

extern "C" void kernel_launch(void* const* d_in, const int* in_sizes, int n_in,
                              void* d_out, int out_size, void* d_ws, size_t ws_size,
                              hipStream_t stream) {
  const float* x    = (const float*)d_in[0];
  const float* Wqkv = (const float*)d_in[1];
  const float* bqkv = (const float*)d_in[2];
  const float* Wo   = (const float*)d_in[3];
  const float* bo   = (const float*)d_in[4];
  const float* sink = (const float*)d_in[5];

  // workspace layout (48 MB total):
  //  0- 8 MB : xb (x bf16; dead after gemm1)  /  zb (attn out; aliases xb)
  //  8-14 MB : W_QKV^T bf16
  // 14-16 MB : W_O^T bf16
  // 16-24 MB : Vt[bh][d][t] bf16 (written by gemm1 epilogue)
  // 24-48 MB : qkv bf16 (Q,K used; V region unwritten)
  char* ws = (char*)d_ws;
  uint16_t* xb    = (uint16_t*)(ws);
  uint16_t* zb    = (uint16_t*)(ws);
  uint16_t* wqkvt = (uint16_t*)(ws + (size_t)8  * 1048576);
  uint16_t* wot   = (uint16_t*)(ws + (size_t)14 * 1048576);
  uint16_t* vtb   = (uint16_t*)(ws + (size_t)16 * 1048576);
  uint16_t* qkvb  = (uint16_t*)(ws + (size_t)24 * 1048576);

  k_prep<<<5120, 256, 0, stream>>>(x, Wqkv, Wo, xb, wqkvt, wot);
  k_gemm_bt<true, true, true><<<dim3(M_ / 128, N3_ / 128), 256, 0, stream>>>(
      xb, wqkvt, bqkv, qkvb, vtb, M_, N3_, D_);
  k_attn6<<<dim3(512), 512, 0, stream>>>(qkvb, vtb, sink, zb);
  k_gemm_bt<false, false, false><<<dim3(M_ / 128, D_ / 128), 256, 0, stream>>>(
      zb, wot, bo, d_out, nullptr, M_, D_, D_);
}